// Round 1
// baseline (268.228 us; speedup 1.0000x reference)
//
#include <hip/hip_runtime.h>
#include <stdint.h>

#define DEVFN __device__ __forceinline__

typedef unsigned short u16;
typedef __bf16 bf16_t;
typedef bf16_t bf16x8 __attribute__((ext_vector_type(8)));
typedef float  f32x4  __attribute__((ext_vector_type(4)));

static constexpr int Bb = 8, Nn = 3072, Cc = 768;
static constexpr int Mr = Bb * Nn;      // 24576 rows
static constexpr int C3 = 3 * Cc;       // 2304
static constexpr int NB = 1024;         // dilation stride / windows per (dil,b,head)

DEVFN u16 f2bf_rne(float f) {
  uint32_t u = __builtin_bit_cast(uint32_t, f);
  u += 0x7FFFu + ((u >> 16) & 1u);
  return (u16)(u >> 16);
}
DEVFN float bf2f(u16 v) {
  uint32_t u = ((uint32_t)v) << 16;
  return __builtin_bit_cast(float, u);
}

// ---------------- f32 -> bf16 convert, 4 elems/thread ----------------
__global__ void cvt_f32_bf16(const float4* __restrict__ in, ushort4* __restrict__ out, int n4) {
  int i = blockIdx.x * blockDim.x + threadIdx.x;
  int stride = gridDim.x * blockDim.x;
  for (; i < n4; i += stride) {
    float4 v = in[i];
    ushort4 o;
    o.x = f2bf_rne(v.x); o.y = f2bf_rne(v.y);
    o.z = f2bf_rne(v.z); o.w = f2bf_rne(v.w);
    out[i] = o;
  }
}

// ---------------- async global->LDS, 16B per lane ----------------
DEVFN void gload_lds16(const void* g, void* l) {
  __builtin_amdgcn_global_load_lds(
      (const __attribute__((address_space(1))) uint32_t*)g,
      (__attribute__((address_space(3))) uint32_t*)l,
      16, 0, 0);
}

// ---------------- bf16 NT GEMM: C[M,N] = A[M,K] * B[N,K]^T (+bias) ----------------
// m97-style: 128x128 tile, BK=32, 4 waves (2x2), 4x4 16x16x32 frags per wave.
template <bool OUT_F32>
__global__ __launch_bounds__(256)
void gemm_bt(const u16* __restrict__ A, const u16* __restrict__ Bw,
             void* __restrict__ Cout, const float* __restrict__ bias,
             int Ndim, int K) {
  constexpr int BM = 128, BN = 128, BK = 32;
  __shared__ u16 As[BM * BK];
  __shared__ u16 Bs[BN * BK];

  const int nTn = Ndim / BN;
  const int tm = blockIdx.x / nTn;
  const int tn = blockIdx.x % nTn;

  const int t = threadIdx.x;
  const int lane = t & 63;
  const int wv = t >> 6;
  const int wr = (wv >> 1) * 64;   // wave row offset in tile
  const int wc = (wv & 1) * 64;    // wave col offset in tile

  // staging: chunk c in [0,512), 16B each; chunk c covers row=c>>2, k8=(c&3)*8
  const int r0 = t >> 2, k0 = (t & 3) * 8;   // chunk t
  const int r1 = r0 + 64;                    // chunk t+256 (same k0)
  const u16* gA = A + (size_t)(tm * BM) * K;
  const u16* gB = Bw + (size_t)(tn * BN) * K;

  f32x4 acc[4][4];
  #pragma unroll
  for (int i = 0; i < 4; ++i)
    #pragma unroll
    for (int j = 0; j < 4; ++j)
      acc[i][j] = f32x4{0.f, 0.f, 0.f, 0.f};

  const int lr = lane & 15;          // fragment row (A) / col (B)
  const int lk = (lane >> 4) * 8;    // fragment k offset

  for (int kt = 0; kt < K; kt += BK) {
    gload_lds16(gA + (size_t)r0 * K + kt + k0, &As[(size_t)t * 8]);
    gload_lds16(gA + (size_t)r1 * K + kt + k0, &As[(size_t)(t + 256) * 8]);
    gload_lds16(gB + (size_t)r0 * K + kt + k0, &Bs[(size_t)t * 8]);
    gload_lds16(gB + (size_t)r1 * K + kt + k0, &Bs[(size_t)(t + 256) * 8]);
    __syncthreads();   // compiler emits vmcnt(0) drain before barrier

    bf16x8 af[4], bf[4];
    #pragma unroll
    for (int m = 0; m < 4; ++m)
      af[m] = *reinterpret_cast<const bf16x8*>(&As[(wr + m * 16 + lr) * BK + lk]);
    #pragma unroll
    for (int n = 0; n < 4; ++n)
      bf[n] = *reinterpret_cast<const bf16x8*>(&Bs[(wc + n * 16 + lr) * BK + lk]);
    #pragma unroll
    for (int m = 0; m < 4; ++m)
      #pragma unroll
      for (int n = 0; n < 4; ++n)
        acc[m][n] = __builtin_amdgcn_mfma_f32_16x16x32_bf16(af[m], bf[n], acc[m][n], 0, 0, 0);
    __syncthreads();
  }

  // epilogue: C/D layout col=lane&15, row=(lane>>4)*4+j  [verified m89/m91]
  const int rbase = tm * BM + wr + (lane >> 4) * 4;
  #pragma unroll
  for (int m = 0; m < 4; ++m) {
    #pragma unroll
    for (int n = 0; n < 4; ++n) {
      const int col = tn * BN + wc + n * 16 + lr;
      const int row0 = rbase + m * 16;
      if (OUT_F32) {
        float* O = (float*)Cout;
        const float bv = bias[col];
        #pragma unroll
        for (int j = 0; j < 4; ++j)
          O[(size_t)(row0 + j) * Ndim + col] = acc[m][n][j] + bv;
      } else {
        u16* O = (u16*)Cout;
        #pragma unroll
        for (int j = 0; j < 4; ++j)
          O[(size_t)(row0 + j) * Ndim + col] = f2bf_rne(acc[m][n][j]);
      }
    }
  }
}

// ---------------- local 3x3 dilated attention, one wave per window ----------------
// qkv: [b][n][2304] bf16 (col = which*768 + dil*256 + head*64 + hi)
// y:   [b][n][768]  bf16 (GEMM2 input layout)
__global__ __launch_bounds__(256)
void attn_local(const u16* __restrict__ qkv, u16* __restrict__ y) {
  const int t = threadIdx.x;
  const int wv = t >> 6, lane = t & 63;
  int wid = blockIdx.x * 4 + wv;            // [0, 3*8*4*1024)
  const int w = wid & (NB - 1); wid >>= 10;
  const int head = wid & 3; wid >>= 2;
  const int b = wid & 7; wid >>= 3;
  const int dil = wid;                      // 0..2

  const int colq = dil * 256 + head * 64 + lane;
  float q[3], k[3], v[3];
  #pragma unroll
  for (int i = 0; i < 3; ++i) {
    const size_t row = (size_t)(b * Nn + i * NB + w) * C3;
    q[i] = bf2f(qkv[row + colq]);
    k[i] = bf2f(qkv[row + 768 + colq]);
    v[i] = bf2f(qkv[row + 1536 + colq]);
  }

  // scores s[i][j] = scale * <q_i, k_j> over 64 lanes
  float s[3][3];
  #pragma unroll
  for (int i = 0; i < 3; ++i)
    #pragma unroll
    for (int j = 0; j < 3; ++j) {
      float p = q[i] * k[j];
      #pragma unroll
      for (int off = 32; off > 0; off >>= 1)
        p += __shfl_xor(p, off, 64);
      s[i][j] = p * 0.125f;   // hd=64 -> scale 1/8
    }

  #pragma unroll
  for (int i = 0; i < 3; ++i) {
    const float mx = fmaxf(fmaxf(s[i][0], s[i][1]), s[i][2]);
    const float e0 = __expf(s[i][0] - mx);
    const float e1 = __expf(s[i][1] - mx);
    const float e2 = __expf(s[i][2] - mx);
    const float inv = 1.0f / (e0 + e1 + e2);
    const float o = (e0 * v[0] + e1 * v[1] + e2 * v[2]) * inv;
    const int linear = head * 192 + i * 64 + lane;     // [0,768)
    const int nout = w * 3 + (linear >> 8);
    const int dd = linear & 255;
    y[(size_t)(b * Nn + nout) * Cc + dil * 256 + dd] = f2bf_rne(o);
  }
}

extern "C" void kernel_launch(void* const* d_in, const int* in_sizes, int n_in,
                              void* d_out, int out_size, void* d_ws, size_t ws_size,
                              hipStream_t stream) {
  const float* x      = (const float*)d_in[0];
  const float* qkv_w  = (const float*)d_in[1];
  const float* proj_w = (const float*)d_in[2];
  const float* proj_b = (const float*)d_in[3];

  char* ws = (char*)d_ws;
  u16* wq_b = (u16*)(ws);                      //  2304*768 bf16 = 3.54 MB
  u16* wp_b = (u16*)(ws + 3538944);            //   768*768 bf16 = 1.18 MB
  u16* xb   = (u16*)(ws + 4718592);            // 24576*768 bf16 = 37.75 MB (reused as yb)
  u16* qkvb = (u16*)(ws + 42467328);           // 24576*2304 bf16 = 113.25 MB
  u16* yb   = xb;                              // x dead after GEMM1; stream-ordered

  cvt_f32_bf16<<<2048, 256, 0, stream>>>((const float4*)x,      (ushort4*)xb,   Mr * Cc / 4);
  cvt_f32_bf16<<<512,  256, 0, stream>>>((const float4*)qkv_w,  (ushort4*)wq_b, C3 * Cc / 4);
  cvt_f32_bf16<<<256,  256, 0, stream>>>((const float4*)proj_w, (ushort4*)wp_b, Cc * Cc / 4);

  // GEMM1: qkvb[M,2304] = xb[M,768] @ wq_b[2304,768]^T
  gemm_bt<false><<<(Mr / 128) * (C3 / 128), 256, 0, stream>>>(xb, wq_b, qkvb, nullptr, C3, Cc);

  // attention: 98304 windows, 4 per block
  attn_local<<<(3 * 8 * 4 * 1024) / 4, 256, 0, stream>>>(qkvb, yb);

  // GEMM2: out[M,768] = yb[M,768] @ wp_b[768,768]^T + proj_b (fp32)
  gemm_bt<true><<<(Mr / 128) * (Cc / 128), 256, 0, stream>>>(yb, wp_b, d_out, proj_b, Cc, Cc);
}

// Round 2
// 245.262 us; speedup vs baseline: 1.0936x; 1.0936x over previous
//
#include <hip/hip_runtime.h>
#include <stdint.h>

#define DEVFN __device__ __forceinline__

typedef unsigned short u16;
typedef __bf16 bf16_t;
typedef bf16_t bf16x8 __attribute__((ext_vector_type(8)));
typedef float  f32x4  __attribute__((ext_vector_type(4)));

static constexpr int Bb = 8, Nn = 3072, Cc = 768;
static constexpr int Mr = Bb * Nn;      // 24576 rows
static constexpr int C3 = 3 * Cc;       // 2304
static constexpr int NB = 1024;         // dilation stride

DEVFN u16 f2bf_rne(float f) {
  uint32_t u = __builtin_bit_cast(uint32_t, f);
  u += 0x7FFFu + ((u >> 16) & 1u);
  return (u16)(u >> 16);
}
DEVFN float bf2f(u16 v) {
  uint32_t u = ((uint32_t)v) << 16;
  return __builtin_bit_cast(float, u);
}

// ---------------- f32 -> bf16 convert ----------------
__global__ void cvt_f32_bf16(const float4* __restrict__ in, ushort4* __restrict__ out, int n4) {
  int i = blockIdx.x * blockDim.x + threadIdx.x;
  int stride = gridDim.x * blockDim.x;
  for (; i < n4; i += stride) {
    float4 v = in[i];
    ushort4 o;
    o.x = f2bf_rne(v.x); o.y = f2bf_rne(v.y);
    o.z = f2bf_rne(v.z); o.w = f2bf_rne(v.w);
    out[i] = o;
  }
}

// ---------------- async global->LDS, 16B per lane ----------------
DEVFN void gload_lds16(const void* g, void* l) {
  __builtin_amdgcn_global_load_lds(
      (const __attribute__((address_space(1))) uint32_t*)g,
      (__attribute__((address_space(3))) uint32_t*)l,
      16, 0, 0);
}

// =====================================================================
// 256x256 bf16 NT GEMM, 8 waves, 4-deep K-slice ring pipeline (T1-T5).
//   C[M,N] = A[M,K] * B[N,K]^T (+bias, f32 out) or bf16 out.
// K-slice = 32 (one MFMA K-step). LDS ring: 4 slots x (A 16K + B 16K).
// Per phase (one slice): 12 swizzled ds_read_b128, prefetch slice p+3
// (4 global_load_lds, counted vmcnt(8) at phase start), 32 MFMA.
// Swizzle: LDS(r, cb) holds global(r, cb ^ ((r&3)<<4)); applied on the
// global SOURCE addr (linear gload_lds dest) and on the ds_read addr.
// =====================================================================
template <bool OUT_F32>
__global__ __launch_bounds__(512, 2)
void gemm256(const u16* __restrict__ A, const u16* __restrict__ Bw,
             void* __restrict__ Cout, const float* __restrict__ bias,
             int Ndim, int K) {
  constexpr int SLOT = 32768;
  __shared__ char lds[4 * SLOT];   // 128 KiB

  const int nTn = Ndim >> 8;
  const int nwg = gridDim.x;
  const int bid = blockIdx.x;
  const int wgid = (bid & 7) * (nwg >> 3) + (bid >> 3);   // XCD swizzle (nwg%8==0)
  const int tm = wgid / nTn, tn = wgid % nTn;

  const int t = threadIdx.x;
  const int l = t & 63;
  const int w = t >> 6;          // wave 0..7
  const int wr = w >> 2;         // M half of tile
  const int wcq = w & 3;         // N quarter of tile
  const int lr = l & 15;

  const int NPH = K >> 5;        // 32-wide K slices

  // staging source (per-lane, pre-swizzled col within the 32-slice)
  const int srow = l >> 2;                       // row within 16-row chunk
  const int scol = 8 * ((l & 3) ^ (srow & 3));   // element col in slice
  const u16* pA0 = A  + (size_t)(tm * 256 +       w * 16 + srow) * K + scol;
  const u16* pA1 = A  + (size_t)(tm * 256 + 128 + w * 16 + srow) * K + scol;
  const u16* pB0 = Bw + (size_t)(tn * 256 +       w * 16 + srow) * K + scol;
  const u16* pB1 = Bw + (size_t)(tn * 256 + 128 + w * 16 + srow) * K + scol;

  // ds_read per-lane offset (swizzled): row lr, k-part (l>>4)*8
  const int lane_off = lr * 64 + (((l >> 4) * 16) ^ ((lr & 3) << 4));

  f32x4 acc[8][4];
  #pragma unroll
  for (int m = 0; m < 8; ++m)
    #pragma unroll
    for (int n = 0; n < 4; ++n)
      acc[m][n] = f32x4{0.f, 0.f, 0.f, 0.f};

  // prologue: stage slices 0,1,2 (12 vmem instrs/wave in flight)
  #pragma unroll
  for (int q = 0; q < 3; ++q) {
    char* dA = &lds[q * SLOT + w * 1024];
    char* dB = &lds[q * SLOT + 16384 + w * 1024];
    const size_t ko = (size_t)q * 32;
    gload_lds16(pA0 + ko, dA);
    gload_lds16(pA1 + ko, dA + 8192);
    gload_lds16(pB0 + ko, dB);
    gload_lds16(pB1 + ko, dB + 8192);
  }

#define GPHASE(VMSTR, PF_COND)                                                \
  do {                                                                        \
    asm volatile(VMSTR ::: "memory");                                         \
    __builtin_amdgcn_s_barrier();                                             \
    asm volatile("" ::: "memory");                                            \
    const char* ab = &lds[(p & 3) * SLOT] + wr * 8192 + lane_off;             \
    const char* bb = &lds[(p & 3) * SLOT + 16384] + wcq * 4096 + lane_off;    \
    bf16x8 af[8], bf[4];                                                      \
    _Pragma("unroll")                                                         \
    for (int m = 0; m < 8; ++m)                                               \
      af[m] = *reinterpret_cast<const bf16x8*>(ab + m * 1024);                \
    _Pragma("unroll")                                                         \
    for (int n = 0; n < 4; ++n)                                               \
      bf[n] = *reinterpret_cast<const bf16x8*>(bb + n * 1024);                \
    if (PF_COND) {                                                            \
      const int ps = (p + 3) & 3;                                             \
      char* dA = &lds[ps * SLOT + w * 1024];                                  \
      char* dB = &lds[ps * SLOT + 16384 + w * 1024];                          \
      const size_t ko = (size_t)(p + 3) * 32;                                 \
      gload_lds16(pA0 + ko, dA);                                              \
      gload_lds16(pA1 + ko, dA + 8192);                                       \
      gload_lds16(pB0 + ko, dB);                                              \
      gload_lds16(pB1 + ko, dB + 8192);                                       \
    }                                                                         \
    __builtin_amdgcn_s_setprio(1);                                            \
    _Pragma("unroll")                                                         \
    for (int m = 0; m < 8; ++m)                                               \
      _Pragma("unroll")                                                       \
      for (int n = 0; n < 4; ++n)                                             \
        acc[m][n] = __builtin_amdgcn_mfma_f32_16x16x32_bf16(af[m], bf[n],     \
                                                            acc[m][n], 0,0,0);\
    __builtin_amdgcn_s_setprio(0);                                            \
    asm volatile("" ::: "memory");                                            \
  } while (0)

  int p = 0;
  for (; p < NPH - 2; ++p) GPHASE("s_waitcnt vmcnt(8)", (p + 3 < NPH));
  GPHASE("s_waitcnt vmcnt(4)", false); ++p;
  GPHASE("s_waitcnt vmcnt(0)", false); ++p;
#undef GPHASE

  // epilogue: C/D layout col=lane&15, row=(lane>>4)*4+j
  const int rb = tm * 256 + wr * 128 + (l >> 4) * 4;
  const int cbase = tn * 256 + wcq * 64 + lr;
  #pragma unroll
  for (int m = 0; m < 8; ++m) {
    #pragma unroll
    for (int n = 0; n < 4; ++n) {
      const int col = cbase + n * 16;
      const int row0 = rb + m * 16;
      if constexpr (OUT_F32) {
        float* O = (float*)Cout;
        const float bv = bias[col];
        #pragma unroll
        for (int j = 0; j < 4; ++j)
          O[(size_t)(row0 + j) * Ndim + col] = acc[m][n][j] + bv;
      } else {
        u16* O = (u16*)Cout;
        #pragma unroll
        for (int j = 0; j < 4; ++j)
          O[(size_t)(row0 + j) * Ndim + col] = f2bf_rne(acc[m][n][j]);
      }
    }
  }
}

// ---------------- local 3x3 dilated attention, one wave per window ----------------
__global__ __launch_bounds__(256)
void attn_local(const u16* __restrict__ qkv, u16* __restrict__ y) {
  const int t = threadIdx.x;
  const int wv = t >> 6, lane = t & 63;
  int wid = blockIdx.x * 4 + wv;
  const int w = wid & (NB - 1); wid >>= 10;
  const int head = wid & 3; wid >>= 2;
  const int b = wid & 7; wid >>= 3;
  const int dil = wid;

  const int colq = dil * 256 + head * 64 + lane;
  float q[3], k[3], v[3];
  #pragma unroll
  for (int i = 0; i < 3; ++i) {
    const size_t row = (size_t)(b * Nn + i * NB + w) * C3;
    q[i] = bf2f(qkv[row + colq]);
    k[i] = bf2f(qkv[row + 768 + colq]);
    v[i] = bf2f(qkv[row + 1536 + colq]);
  }

  float s[3][3];
  #pragma unroll
  for (int i = 0; i < 3; ++i)
    #pragma unroll
    for (int j = 0; j < 3; ++j) {
      float p = q[i] * k[j];
      #pragma unroll
      for (int off = 32; off > 0; off >>= 1)
        p += __shfl_xor(p, off, 64);
      s[i][j] = p * 0.125f;
    }

  #pragma unroll
  for (int i = 0; i < 3; ++i) {
    const float mx = fmaxf(fmaxf(s[i][0], s[i][1]), s[i][2]);
    const float e0 = __expf(s[i][0] - mx);
    const float e1 = __expf(s[i][1] - mx);
    const float e2 = __expf(s[i][2] - mx);
    const float inv = 1.0f / (e0 + e1 + e2);
    const float o = (e0 * v[0] + e1 * v[1] + e2 * v[2]) * inv;
    const int linear = head * 192 + i * 64 + lane;
    const int nout = w * 3 + (linear >> 8);
    const int dd = linear & 255;
    y[(size_t)(b * Nn + nout) * Cc + dil * 256 + dd] = f2bf_rne(o);
  }
}

extern "C" void kernel_launch(void* const* d_in, const int* in_sizes, int n_in,
                              void* d_out, int out_size, void* d_ws, size_t ws_size,
                              hipStream_t stream) {
  const float* x      = (const float*)d_in[0];
  const float* qkv_w  = (const float*)d_in[1];
  const float* proj_w = (const float*)d_in[2];
  const float* proj_b = (const float*)d_in[3];

  char* ws = (char*)d_ws;
  u16* wq_b = (u16*)(ws);                      //  2304*768 bf16
  u16* wp_b = (u16*)(ws + 3538944);            //   768*768 bf16
  u16* xb   = (u16*)(ws + 4718592);            // 24576*768 bf16 (reused as yb)
  u16* qkvb = (u16*)(ws + 42467328);           // 24576*2304 bf16
  u16* yb   = xb;

  cvt_f32_bf16<<<2048, 256, 0, stream>>>((const float4*)x,      (ushort4*)xb,   Mr * Cc / 4);
  cvt_f32_bf16<<<512,  256, 0, stream>>>((const float4*)qkv_w,  (ushort4*)wq_b, C3 * Cc / 4);
  cvt_f32_bf16<<<256,  256, 0, stream>>>((const float4*)proj_w, (ushort4*)wp_b, Cc * Cc / 4);

  // GEMM1: qkvb[M,2304] = xb[M,768] @ wq_b[2304,768]^T   (864 blocks)
  gemm256<false><<<(Mr / 256) * (C3 / 256), 512, 0, stream>>>(xb, wq_b, qkvb, nullptr, C3, Cc);

  // attention: 98304 windows, 4 per block
  attn_local<<<(3 * 8 * 4 * 1024) / 4, 256, 0, stream>>>(qkvb, yb);

  // GEMM2: out[M,768] = yb[M,768] @ wp_b[768,768]^T + proj_b   (288 blocks)
  gemm256<true><<<(Mr / 256) * (Cc / 256), 512, 0, stream>>>(yb, wp_b, d_out, proj_b, Cc, Cc);
}